// Round 1
// baseline (1093.080 us; speedup 1.0000x reference)
//
#include <hip/hip_runtime.h>

// Linear attention (Shen 2018), B=2, N=16384, D=512, H=8, DK=64.
// Pipeline:
//   1) expk = exp(key@Wk + bk)        -> bf16  (ws region A lo)
//   2) vp   = value@Wv + bv           -> bf16  (ws region A hi)
//   3) partial[bh][chunk] = E^T V (+ column sums)  (ws PART)
//   4) reduce partials -> ctx = (E^T V) / s        (ws CTX)
//   5) Mbig[b] = stack_h(ctx_h @ Wo_h)             (ws MBIG)
//   6) qsm = softmax_head(query@Wq + bq)/8 -> f32  (ws region A, reused)
//   7) out = qsm @ Mbig[b] + bo                    (d_out)
// All GEMM compute f32; only exp(K)/V intermediates stored bf16
// (0.4% weight perturbation -> ~1e-5 abs out error vs 8e-5 threshold).

using u16 = unsigned short;

#define D_MODEL 512
#define NHEAD 8
#define DK 64
#define BATCH 2
#define SEQ 16384
#define ROWS (BATCH * SEQ)       // 32768
#define NCHUNK 32
#define CHUNKROWS (SEQ / NCHUNK) // 512

// ---- ws layout (bytes) ----
#define EXPK_OFF 0u
#define EXPK_BYTES (ROWS * D_MODEL * 2)            // 33,554,432
#define VP_OFF (EXPK_OFF + EXPK_BYTES)
#define VP_BYTES (ROWS * D_MODEL * 2)
#define PART_OFF (VP_OFF + VP_BYTES)               // 67,108,864
#define PART_BYTES (BATCH * NHEAD * NCHUNK * 65 * 64 * 4)  // 8,519,680
#define CTX_OFF (PART_OFF + PART_BYTES)            // 75,628,544
#define CTX_BYTES (BATCH * NHEAD * DK * DK * 4)    // 262,144
#define MBIG_OFF (CTX_OFF + CTX_BYTES)             // 75,890,688
#define MBIG_BYTES (BATCH * D_MODEL * D_MODEL * 4) // 2,097,152
#define WS_NEEDED (MBIG_OFF + MBIG_BYTES)          // 77,987,840
// qsm (f32, 67,108,864 B) reuses [EXPK_OFF, PART_OFF) after step 3.

__device__ __forceinline__ float bf2f(u16 u) {
  union { unsigned int i; float f; } x; x.i = ((unsigned int)u) << 16; return x.f;
}
__device__ __forceinline__ u16 f2bf(float f) {
  union { float ff; unsigned int i; } x; x.ff = f;
  unsigned int r = x.i + 0x7fffu + ((x.i >> 16) & 1u);  // RNE
  return (u16)(r >> 16);
}

// ---------------- projection GEMM: C[64x64 tile] = A @ W + bias, epilogue ----
// EPI: 0 = per-head softmax(/8) -> f32 ; 1 = exp -> bf16 ; 2 = plain -> bf16
template <int EPI>
__launch_bounds__(256)
__global__ void proj_kernel(const float* __restrict__ A, const float* __restrict__ W,
                            const float* __restrict__ bias,
                            float* __restrict__ outf, u16* __restrict__ outb) {
  __shared__ float Alds[16][65];  // [k][row], +1 pad breaks store conflicts
  __shared__ float Wlds[16][64];  // [k][col]
  const int t = threadIdx.x;
  const int tx = t & 15, ty = t >> 4;
  const int row0 = blockIdx.x << 6;   // 512 row tiles
  const int col0 = blockIdx.y << 6;   // 8 col tiles (= head index for EPI 0)
  const int ar = t >> 2, ak = (t & 3) << 2;  // A staging: row 0..63, k 0/4/8/12
  float acc[4][4] = {};
  for (int k0 = 0; k0 < D_MODEL; k0 += 16) {
    const float4 av = *(const float4*)(A + (row0 + ar) * D_MODEL + k0 + ak);
    const float4 wv = *(const float4*)(W + (k0 + ty) * D_MODEL + col0 + (tx << 2));
    __syncthreads();  // prior iteration LDS reads done
    Alds[ak + 0][ar] = av.x; Alds[ak + 1][ar] = av.y;
    Alds[ak + 2][ar] = av.z; Alds[ak + 3][ar] = av.w;
    *(float4*)(&Wlds[ty][tx << 2]) = wv;
    __syncthreads();
#pragma unroll
    for (int k = 0; k < 16; ++k) {
      float a[4], w[4];
#pragma unroll
      for (int i = 0; i < 4; ++i) a[i] = Alds[k][(ty << 2) + i];  // broadcast
#pragma unroll
      for (int j = 0; j < 4; ++j) w[j] = Wlds[k][(tx << 2) + j];  // 2-way=free
#pragma unroll
      for (int i = 0; i < 4; ++i)
#pragma unroll
        for (int j = 0; j < 4; ++j) acc[i][j] = fmaf(a[i], w[j], acc[i][j]);
    }
  }
  {  // bias (zeros in this problem, kept for exact reference semantics)
    float bv[4];
#pragma unroll
    for (int j = 0; j < 4; ++j) bv[j] = bias[col0 + (tx << 2) + j];
#pragma unroll
    for (int i = 0; i < 4; ++i)
#pragma unroll
      for (int j = 0; j < 4; ++j) acc[i][j] += bv[j];
  }
  if constexpr (EPI == 0) {
    // per-row softmax over this 64-col tile (one full head), then *1/8
    __shared__ float Cs[64][65];
    __shared__ float mrow[64], srow[64];
#pragma unroll
    for (int i = 0; i < 4; ++i)
#pragma unroll
      for (int j = 0; j < 4; ++j) Cs[(ty << 2) + i][(tx << 2) + j] = acc[i][j];
    __syncthreads();
    if (t < 64) {
      float m = -1e30f;
      for (int c = 0; c < 64; ++c) m = fmaxf(m, Cs[t][c]);
      float s = 0.f;
      for (int c = 0; c < 64; ++c) s += expf(Cs[t][c] - m);
      mrow[t] = m; srow[t] = s;
    }
    __syncthreads();
#pragma unroll
    for (int i = 0; i < 4; ++i) {
      const int r = (ty << 2) + i;
      const float m = mrow[r];
      const float inv = 0.125f / srow[r];
      float4 o;
      o.x = expf(acc[i][0] - m) * inv; o.y = expf(acc[i][1] - m) * inv;
      o.z = expf(acc[i][2] - m) * inv; o.w = expf(acc[i][3] - m) * inv;
      *(float4*)(outf + (row0 + r) * D_MODEL + col0 + (tx << 2)) = o;
    }
  } else if constexpr (EPI == 1) {
#pragma unroll
    for (int i = 0; i < 4; ++i) {
      const int r = (ty << 2) + i;
      ushort4 o;
      o.x = f2bf(expf(acc[i][0])); o.y = f2bf(expf(acc[i][1]));
      o.z = f2bf(expf(acc[i][2])); o.w = f2bf(expf(acc[i][3]));
      *(ushort4*)(outb + (row0 + r) * D_MODEL + col0 + (tx << 2)) = o;
    }
  } else {
#pragma unroll
    for (int i = 0; i < 4; ++i) {
      const int r = (ty << 2) + i;
      ushort4 o;
      o.x = f2bf(acc[i][0]); o.y = f2bf(acc[i][1]);
      o.z = f2bf(acc[i][2]); o.w = f2bf(acc[i][3]);
      *(ushort4*)(outb + (row0 + r) * D_MODEL + col0 + (tx << 2)) = o;
    }
  }
}

// -------- per-(b,h) partial ctx_un = E_chunk^T V_chunk and partial s = Σ E --
__launch_bounds__(256)
__global__ void ctx_partial_kernel(const u16* __restrict__ expk, const u16* __restrict__ vp,
                                   float* __restrict__ part) {
  __shared__ float Elds[16][65];  // [n][d]
  __shared__ float Vlds[16][64];  // [n][e]
  const int t = threadIdx.x;
  const int tx = t & 15, ty = t >> 4;
  const int chunk = blockIdx.x;  // 0..NCHUNK-1
  const int bh = blockIdx.y;     // 0..15
  const int b = bh >> 3, h = bh & 7;
  const int base = b * SEQ * D_MODEL + h * DK;
  const int n0 = chunk * CHUNKROWS;
  const int lr = t >> 4, lc = (t & 15) << 2;
  float acc[4][4] = {};
  float sp = 0.f;
  for (int nn = 0; nn < CHUNKROWS; nn += 16) {
    const int goff = base + (n0 + nn + lr) * D_MODEL + lc;
    const ushort4 e4 = *(const ushort4*)(expk + goff);
    const ushort4 v4 = *(const ushort4*)(vp + goff);
    __syncthreads();
    Elds[lr][lc + 0] = bf2f(e4.x); Elds[lr][lc + 1] = bf2f(e4.y);
    Elds[lr][lc + 2] = bf2f(e4.z); Elds[lr][lc + 3] = bf2f(e4.w);
    Vlds[lr][lc + 0] = bf2f(v4.x); Vlds[lr][lc + 1] = bf2f(v4.y);
    Vlds[lr][lc + 2] = bf2f(v4.z); Vlds[lr][lc + 3] = bf2f(v4.w);
    __syncthreads();
#pragma unroll
    for (int k = 0; k < 16; ++k) {
      float e[4], v[4];
#pragma unroll
      for (int i = 0; i < 4; ++i) e[i] = Elds[k][(ty << 2) + i];
#pragma unroll
      for (int j = 0; j < 4; ++j) v[j] = Vlds[k][(tx << 2) + j];
#pragma unroll
      for (int i = 0; i < 4; ++i)
#pragma unroll
        for (int j = 0; j < 4; ++j) acc[i][j] = fmaf(e[i], v[j], acc[i][j]);
    }
    if (t < 64) {  // fold the column-sum pass into the same staging
      float ss = 0.f;
#pragma unroll
      for (int k = 0; k < 16; ++k) ss += Elds[k][t];
      sp += ss;
    }
  }
  float* pp = part + (bh * NCHUNK + chunk) * (65 * 64);
#pragma unroll
  for (int i = 0; i < 4; ++i)
#pragma unroll
    for (int j = 0; j < 4; ++j)
      pp[((ty << 2) + i) * 64 + (tx << 2) + j] = acc[i][j];
  if (t < 64) pp[64 * 64 + t] = sp;
}

// -------- reduce partials over chunks, normalize: ctx = un / s --------------
__launch_bounds__(256)
__global__ void ctx_reduce_kernel(const float* __restrict__ part, float* __restrict__ ctx) {
  __shared__ float buf[65 * 64];
  const int bh = blockIdx.x;
  const int t = threadIdx.x;
  for (int idx = t; idx < 65 * 64; idx += 256) {
    float s = 0.f;
    for (int c = 0; c < NCHUNK; ++c) s += part[(bh * NCHUNK + c) * (65 * 64) + idx];
    buf[idx] = s;
  }
  __syncthreads();
  for (int idx = t; idx < 64 * 64; idx += 256)
    ctx[bh * 4096 + idx] = buf[idx] / buf[64 * 64 + (idx >> 6)];
}

// -------- Mbig[b][h*64+d][c] = Σ_e ctx[b,h,d,e] * Wo[h*64+e][c] -------------
__launch_bounds__(256)
__global__ void mbig_kernel(const float* __restrict__ ctx, const float* __restrict__ Wo,
                            float* __restrict__ Mbig) {
  __shared__ float Clds[64][65];   // [d][e]
  __shared__ float Wlds2[64][64];  // [e][c]
  const int t = threadIdx.x;
  const int tx = t & 15, ty = t >> 4;
  const int cc = blockIdx.x;  // 0..7 column chunk of 64
  const int bh = blockIdx.y;  // 0..15
  const int b = bh >> 3, h = bh & 7;
  const float* ch = ctx + bh * 4096;
  for (int i4 = t; i4 < 1024; i4 += 256) {
    const int r = i4 >> 4, c = (i4 & 15) << 2;
    const float4 v = *(const float4*)(ch + (r << 6) + c);
    Clds[r][c] = v.x; Clds[r][c + 1] = v.y; Clds[r][c + 2] = v.z; Clds[r][c + 3] = v.w;
    const float4 wv = *(const float4*)(Wo + (h * 64 + r) * D_MODEL + cc * 64 + c);
    Wlds2[r][c] = wv.x; Wlds2[r][c + 1] = wv.y; Wlds2[r][c + 2] = wv.z; Wlds2[r][c + 3] = wv.w;
  }
  __syncthreads();
  float acc[4][4] = {};
#pragma unroll 8
  for (int k = 0; k < 64; ++k) {
    float a[4], w[4];
#pragma unroll
    for (int i = 0; i < 4; ++i) a[i] = Clds[(ty << 2) + i][k];
#pragma unroll
    for (int j = 0; j < 4; ++j) w[j] = Wlds2[k][(tx << 2) + j];
#pragma unroll
    for (int i = 0; i < 4; ++i)
#pragma unroll
      for (int j = 0; j < 4; ++j) acc[i][j] = fmaf(a[i], w[j], acc[i][j]);
  }
  float* mp = Mbig + b * D_MODEL * D_MODEL + (h * 64) * D_MODEL + cc * 64;
#pragma unroll
  for (int i = 0; i < 4; ++i) {
    float4 o; o.x = acc[i][0]; o.y = acc[i][1]; o.z = acc[i][2]; o.w = acc[i][3];
    *(float4*)(mp + ((ty << 2) + i) * D_MODEL + (tx << 2)) = o;
  }
}

// -------- out = qsm @ Mbig[b] + bo ------------------------------------------
__launch_bounds__(256)
__global__ void final_kernel(const float* __restrict__ Aq, const float* __restrict__ Mbig,
                             const float* __restrict__ bo, float* __restrict__ out) {
  __shared__ float Alds[16][65];
  __shared__ float Wlds[16][64];
  const int t = threadIdx.x;
  const int tx = t & 15, ty = t >> 4;
  const int row0 = blockIdx.x << 6;
  const int col0 = blockIdx.y << 6;
  const int b = (row0 >= SEQ) ? 1 : 0;  // 64-row tiles never straddle batches
  const float* W = Mbig + b * D_MODEL * D_MODEL;
  const int ar = t >> 2, ak = (t & 3) << 2;
  float acc[4][4] = {};
  for (int k0 = 0; k0 < D_MODEL; k0 += 16) {
    const float4 av = *(const float4*)(Aq + (row0 + ar) * D_MODEL + k0 + ak);
    const float4 wv = *(const float4*)(W + (k0 + ty) * D_MODEL + col0 + (tx << 2));
    __syncthreads();
    Alds[ak + 0][ar] = av.x; Alds[ak + 1][ar] = av.y;
    Alds[ak + 2][ar] = av.z; Alds[ak + 3][ar] = av.w;
    *(float4*)(&Wlds[ty][tx << 2]) = wv;
    __syncthreads();
#pragma unroll
    for (int k = 0; k < 16; ++k) {
      float a[4], w[4];
#pragma unroll
      for (int i = 0; i < 4; ++i) a[i] = Alds[k][(ty << 2) + i];
#pragma unroll
      for (int j = 0; j < 4; ++j) w[j] = Wlds[k][(tx << 2) + j];
#pragma unroll
      for (int i = 0; i < 4; ++i)
#pragma unroll
        for (int j = 0; j < 4; ++j) acc[i][j] = fmaf(a[i], w[j], acc[i][j]);
    }
  }
  float bv[4];
#pragma unroll
  for (int j = 0; j < 4; ++j) bv[j] = bo[col0 + (tx << 2) + j];
#pragma unroll
  for (int i = 0; i < 4; ++i) {
    float4 o;
    o.x = acc[i][0] + bv[0]; o.y = acc[i][1] + bv[1];
    o.z = acc[i][2] + bv[2]; o.w = acc[i][3] + bv[3];
    *(float4*)(out + (row0 + (ty << 2) + i) * D_MODEL + col0 + (tx << 2)) = o;
  }
}

__global__ void sentinel_kernel(float* out) { out[0] = 1.0e9f; }  // ws too small marker

extern "C" void kernel_launch(void* const* d_in, const int* in_sizes, int n_in,
                              void* d_out, int out_size, void* d_ws, size_t ws_size,
                              hipStream_t stream) {
  const float* query = (const float*)d_in[0];
  const float* key   = (const float*)d_in[1];
  const float* value = (const float*)d_in[2];
  const float* Wq = (const float*)d_in[3];
  const float* bq = (const float*)d_in[4];
  const float* Wk = (const float*)d_in[5];
  const float* bk = (const float*)d_in[6];
  const float* Wv = (const float*)d_in[7];
  const float* bv = (const float*)d_in[8];
  const float* Wo = (const float*)d_in[9];
  const float* bo = (const float*)d_in[10];
  float* out = (float*)d_out;
  char* ws = (char*)d_ws;

  if (ws_size < (size_t)WS_NEEDED) {  // unambiguous failure signature
    sentinel_kernel<<<1, 1, 0, stream>>>(out);
    return;
  }

  u16* expk  = (u16*)(ws + EXPK_OFF);
  u16* vp    = (u16*)(ws + VP_OFF);
  float* part = (float*)(ws + PART_OFF);
  float* ctx  = (float*)(ws + CTX_OFF);
  float* Mbig = (float*)(ws + MBIG_OFF);
  float* qsm  = (float*)(ws + EXPK_OFF);  // reuse: expk/vp dead after ctx_partial

  const dim3 gproj(ROWS / 64, D_MODEL / 64), blk(256);
  proj_kernel<1><<<gproj, blk, 0, stream>>>(key, Wk, bk, nullptr, expk);
  proj_kernel<2><<<gproj, blk, 0, stream>>>(value, Wv, bv, nullptr, vp);
  ctx_partial_kernel<<<dim3(NCHUNK, BATCH * NHEAD), blk, 0, stream>>>(expk, vp, part);
  ctx_reduce_kernel<<<BATCH * NHEAD, 256, 0, stream>>>(part, ctx);
  mbig_kernel<<<dim3(8, BATCH * NHEAD), blk, 0, stream>>>(ctx, Wo, Mbig);
  proj_kernel<0><<<gproj, blk, 0, stream>>>(query, Wq, bq, qsm, nullptr);
  final_kernel<<<gproj, blk, 0, stream>>>(qsm, Mbig, bo, out);
}

// Round 2
// 407.016 us; speedup vs baseline: 2.6856x; 2.6856x over previous
//
#include <hip/hip_runtime.h>

// Linear attention (Shen 2018), B=2, N=16384, D=512, H=8, DK=64.
// Round 2: the four big GEMMs (K/V/Q projections + output) move to
// mfma_f32_16x16x32_bf16 with reg-staged f32->bf16 conversion, T2 XOR-swizzled
// LDS, and XCD-chunked work swizzle. ctx path unchanged from round 1.

using u16 = unsigned short;
typedef __attribute__((ext_vector_type(8))) short bf16x8;
typedef __attribute__((ext_vector_type(4))) float f32x4;

#define D_MODEL 512
#define NHEAD 8
#define DK 64
#define BATCH 2
#define SEQ 16384
#define ROWS (BATCH * SEQ)       // 32768
#define NCHUNK 32
#define CHUNKROWS (SEQ / NCHUNK) // 512

// ---- ws layout (bytes); total must stay <= 77,987,840 (known-safe) ----
#define EXPK_OFF 0u              // 32M bf16 expk; later reused as qsm (bf16)
#define VP_OFF 33554432u         // 32M bf16 vp
#define PART_OFF 67108864u       // 8,519,680 f32 partials (dead after ctx_reduce)
#define WTQ_OFF 67108864u        //   then: 512K bf16 Wq^T
#define MBIGT_OFF 67633152u      //   then: 1M bf16 MbigT[2][512][512]
#define CTX_OFF 75628544u        // 256K f32 ctx
#define WTK_OFF 75890688u        // 512K bf16 Wk^T
#define WTV_OFF 76414976u        // 512K bf16 Wv^T
#define WS_NEEDED 76939264u

__device__ __forceinline__ float bf2f(u16 u) {
  union { unsigned int i; float f; } x; x.i = ((unsigned int)u) << 16; return x.f;
}
__device__ __forceinline__ u16 f2bf(float f) {
  union { float ff; unsigned int i; } x; x.ff = f;
  unsigned int r = x.i + 0x7fffu + ((x.i >> 16) & 1u);  // RNE
  return (u16)(r >> 16);
}
__device__ __forceinline__ unsigned int pk2(float lo, float hi) {
  return (unsigned int)f2bf(lo) | ((unsigned int)f2bf(hi) << 16);
}
// swizzled byte offset into a [128 rows][64 bf16] LDS tile (T2: breaks the
// 16-way conflict of 128B row stride on ds_read_b128)
__device__ __forceinline__ int swz(int row, int kbyte) {
  return row * 128 + (kbyte ^ ((row & 7) << 4));
}

// ---------------- transpose+convert: out[c][r] (bf16) = in[r][c] (f32) ------
__launch_bounds__(256)
__global__ void wcvt_kernel(const float* __restrict__ in, u16* __restrict__ out) {
  __shared__ float S[64][65];
  const int t = threadIdx.x;
  const int i0 = blockIdx.y << 6, j0 = blockIdx.x << 6;
#pragma unroll
  for (int ii = 0; ii < 4; ++ii) {
    const int idx = t + ii * 256;
    const int r = idx >> 4, c4 = (idx & 15) << 2;
    const float4 v = *(const float4*)(in + (i0 + r) * D_MODEL + j0 + c4);
    S[r][c4] = v.x; S[r][c4 + 1] = v.y; S[r][c4 + 2] = v.z; S[r][c4 + 3] = v.w;
  }
  __syncthreads();
#pragma unroll
  for (int ii = 0; ii < 4; ++ii) {
    const int idx = t + ii * 256;
    const int c = idx >> 4, r4 = (idx & 15) << 2;
    ushort4 o;
    o.x = f2bf(S[r4][c]); o.y = f2bf(S[r4 + 1][c]);
    o.z = f2bf(S[r4 + 2][c]); o.w = f2bf(S[r4 + 3][c]);
    *(ushort4*)(out + (j0 + c) * D_MODEL + i0 + r4) = o;
  }
}

// ---------------- MFMA GEMM: C[128x128] = A[.,512] @ BT^T, epilogue ---------
// EPI: 0 = per-head softmax/8 -> bf16 qsm; 1 = exp -> bf16; 2 = plain -> bf16;
//      3 = +bo -> f32 out (B = MbigT per batch)
template <int EPI, bool ABF16>
__launch_bounds__(256)
__global__ void gemm_kernel(const void* __restrict__ Avoid, const u16* __restrict__ BT,
                            const float* __restrict__ bias, void* __restrict__ Ovoid) {
  __shared__ __align__(16) u16 Asw[128 * 64];
  __shared__ __align__(16) u16 Bsw[128 * 64];
  const int t = threadIdx.x;
  const int lane = t & 63, wave = t >> 6;
  const int wm = wave >> 1, wn = wave & 1;
  const int g = lane >> 4, lc = lane & 15;

  // XCD-chunked bijective work swizzle: 1024 wgs, 128 per XCD; within an XCD,
  // the 4 col-tiles of a row-tile are consecutive -> shared A-panel in L2.
  const int flat = (int)blockIdx.x;
  const int work = (flat & 7) * 128 + (flat >> 3);
  const int colt = work & 3, rowt = work >> 2;
  const int row0 = rowt << 7, col0 = colt << 7;

  const u16* BTb = BT;
  if constexpr (EPI == 3) BTb += (row0 >= SEQ ? 1 : 0) * D_MODEL * D_MODEL;

  const int sr = t >> 1, sh = t & 1;  // staging: row/col 0..127, k-half 0..1
  char* As = (char*)Asw;
  char* Bs = (char*)Bsw;

  f32x4 acc[4][4];
#pragma unroll
  for (int m = 0; m < 4; ++m)
#pragma unroll
    for (int n = 0; n < 4; ++n) acc[m][n] = (f32x4){0.f, 0.f, 0.f, 0.f};

  // fragment LDS byte offsets (k0-independent)
  int aoff[4][2], boff[4][2];
#pragma unroll
  for (int m = 0; m < 4; ++m) {
    const int r = wm * 64 + m * 16 + lc;
#pragma unroll
    for (int kk = 0; kk < 2; ++kk) aoff[m][kk] = swz(r, kk * 64 + g * 16);
  }
#pragma unroll
  for (int n = 0; n < 4; ++n) {
    const int c = wn * 64 + n * 16 + lc;
#pragma unroll
    for (int kk = 0; kk < 2; ++kk) boff[n][kk] = swz(c, kk * 64 + g * 16);
  }

  float4 av[8];
  uint4 avb[4];
  uint4 bv[4];

  auto LOADA = [&](int k0) {
    if constexpr (ABF16) {
      const u16* ap = (const u16*)Avoid + (size_t)(row0 + sr) * D_MODEL + k0 + sh * 32;
#pragma unroll
      for (int j = 0; j < 4; ++j) avb[j] = *(const uint4*)(ap + j * 8);
    } else {
      const float* ap = (const float*)Avoid + (size_t)(row0 + sr) * D_MODEL + k0 + sh * 32;
#pragma unroll
      for (int j = 0; j < 8; ++j) av[j] = *(const float4*)(ap + j * 4);
    }
  };
  auto LOADB = [&](int k0) {
    const u16* bp = BTb + (size_t)(col0 + sr) * D_MODEL + k0 + sh * 32;
#pragma unroll
    for (int j = 0; j < 4; ++j) bv[j] = *(const uint4*)(bp + j * 8);
  };
  auto WRITEAB = [&]() {
#pragma unroll
    for (int j = 0; j < 4; ++j) {
      uint4 w;
      if constexpr (ABF16) {
        w = avb[j];
      } else {
        w.x = pk2(av[2 * j].x, av[2 * j].y);
        w.y = pk2(av[2 * j].z, av[2 * j].w);
        w.z = pk2(av[2 * j + 1].x, av[2 * j + 1].y);
        w.w = pk2(av[2 * j + 1].z, av[2 * j + 1].w);
      }
      *(uint4*)(As + swz(sr, sh * 64 + j * 16)) = w;
      *(uint4*)(Bs + swz(sr, sh * 64 + j * 16)) = bv[j];
    }
  };

  LOADA(0); LOADB(0);
  for (int ks = 0; ks < 8; ++ks) {
    __syncthreads();   // prior step's LDS reads complete
    WRITEAB();
    __syncthreads();
    if (ks < 7) { LOADA((ks + 1) * 64); LOADB((ks + 1) * 64); }  // hide under MFMA
#pragma unroll
    for (int kk = 0; kk < 2; ++kk) {
      bf16x8 af[4], bfr[4];
#pragma unroll
      for (int m = 0; m < 4; ++m) af[m] = *(const bf16x8*)(As + aoff[m][kk]);
#pragma unroll
      for (int n = 0; n < 4; ++n) bfr[n] = *(const bf16x8*)(Bs + boff[n][kk]);
#pragma unroll
      for (int m = 0; m < 4; ++m)
#pragma unroll
        for (int n = 0; n < 4; ++n)
          acc[m][n] = __builtin_amdgcn_mfma_f32_16x16x32_bf16(af[m], bfr[n], acc[m][n], 0, 0, 0);
    }
  }

  // ---- epilogue; C/D layout: col = lane&15, row = (lane>>4)*4 + reg ----
  const int orow = row0 + wm * 64;
  const int ocol = col0 + wn * 64;
  float bb[4];
#pragma unroll
  for (int n = 0; n < 4; ++n) bb[n] = bias[ocol + n * 16 + lc];

  if constexpr (EPI == 3) {
    float* O = (float*)Ovoid;
#pragma unroll
    for (int m = 0; m < 4; ++m)
#pragma unroll
      for (int r = 0; r < 4; ++r) {
        const int grow = (orow + m * 16 + g * 4 + r) * D_MODEL + ocol + lc;
#pragma unroll
        for (int n = 0; n < 4; ++n) O[grow + n * 16] = acc[m][n][r] + bb[n];
      }
  } else if constexpr (EPI == 1 || EPI == 2) {
    u16* O = (u16*)Ovoid;
#pragma unroll
    for (int m = 0; m < 4; ++m)
#pragma unroll
      for (int r = 0; r < 4; ++r) {
        const int grow = (orow + m * 16 + g * 4 + r) * D_MODEL + ocol + lc;
#pragma unroll
        for (int n = 0; n < 4; ++n) {
          const float v = acc[m][n][r] + bb[n];
          O[grow + n * 16] = f2bf(EPI == 1 ? __expf(v) : v);
        }
      }
  } else {  // EPI == 0: per-head (64-col = this wave's 4 n-frags) softmax, /8
    u16* O = (u16*)Ovoid;
#pragma unroll
    for (int m = 0; m < 4; ++m)
#pragma unroll
      for (int r = 0; r < 4; ++r) {
        float v[4];
#pragma unroll
        for (int n = 0; n < 4; ++n) v[n] = acc[m][n][r] + bb[n];
        float mx = fmaxf(fmaxf(v[0], v[1]), fmaxf(v[2], v[3]));
#pragma unroll
        for (int msk = 1; msk < 16; msk <<= 1) mx = fmaxf(mx, __shfl_xor(mx, msk));
        float e[4], s = 0.f;
#pragma unroll
        for (int n = 0; n < 4; ++n) { e[n] = __expf(v[n] - mx); s += e[n]; }
#pragma unroll
        for (int msk = 1; msk < 16; msk <<= 1) s += __shfl_xor(s, msk);
        const float sc = 0.125f / s;
        const int grow = (orow + m * 16 + g * 4 + r) * D_MODEL + ocol + lc;
#pragma unroll
        for (int n = 0; n < 4; ++n) O[grow + n * 16] = f2bf(e[n] * sc);
      }
  }
}

// -------- per-(b,h) partial ctx_un = E_chunk^T V_chunk and partial s = Σ E --
__launch_bounds__(256)
__global__ void ctx_partial_kernel(const u16* __restrict__ expk, const u16* __restrict__ vp,
                                   float* __restrict__ part) {
  __shared__ float Elds[16][65];
  __shared__ float Vlds[16][64];
  const int t = threadIdx.x;
  const int tx = t & 15, ty = t >> 4;
  const int chunk = blockIdx.x;
  const int bh = blockIdx.y;
  const int b = bh >> 3, h = bh & 7;
  const int base = b * SEQ * D_MODEL + h * DK;
  const int n0 = chunk * CHUNKROWS;
  const int lr = t >> 4, lcc = (t & 15) << 2;
  float acc[4][4] = {};
  float sp = 0.f;
  for (int nn = 0; nn < CHUNKROWS; nn += 16) {
    const int goff = base + (n0 + nn + lr) * D_MODEL + lcc;
    const ushort4 e4 = *(const ushort4*)(expk + goff);
    const ushort4 v4 = *(const ushort4*)(vp + goff);
    __syncthreads();
    Elds[lr][lcc + 0] = bf2f(e4.x); Elds[lr][lcc + 1] = bf2f(e4.y);
    Elds[lr][lcc + 2] = bf2f(e4.z); Elds[lr][lcc + 3] = bf2f(e4.w);
    Vlds[lr][lcc + 0] = bf2f(v4.x); Vlds[lr][lcc + 1] = bf2f(v4.y);
    Vlds[lr][lcc + 2] = bf2f(v4.z); Vlds[lr][lcc + 3] = bf2f(v4.w);
    __syncthreads();
#pragma unroll
    for (int k = 0; k < 16; ++k) {
      float e[4], v[4];
#pragma unroll
      for (int i = 0; i < 4; ++i) e[i] = Elds[k][(ty << 2) + i];
#pragma unroll
      for (int j = 0; j < 4; ++j) v[j] = Vlds[k][(tx << 2) + j];
#pragma unroll
      for (int i = 0; i < 4; ++i)
#pragma unroll
        for (int j = 0; j < 4; ++j) acc[i][j] = fmaf(e[i], v[j], acc[i][j]);
    }
    if (t < 64) {
      float ss = 0.f;
#pragma unroll
      for (int k = 0; k < 16; ++k) ss += Elds[k][t];
      sp += ss;
    }
  }
  float* pp = part + (bh * NCHUNK + chunk) * (65 * 64);
#pragma unroll
  for (int i = 0; i < 4; ++i)
#pragma unroll
    for (int j = 0; j < 4; ++j)
      pp[((ty << 2) + i) * 64 + (tx << 2) + j] = acc[i][j];
  if (t < 64) pp[64 * 64 + t] = sp;
}

// -------- reduce partials over chunks, normalize: ctx = un / s --------------
__launch_bounds__(256)
__global__ void ctx_reduce_kernel(const float* __restrict__ part, float* __restrict__ ctx) {
  __shared__ float buf[65 * 64];
  const int bh = blockIdx.x;
  const int t = threadIdx.x;
  for (int idx = t; idx < 65 * 64; idx += 256) {
    float s = 0.f;
    for (int c = 0; c < NCHUNK; ++c) s += part[(bh * NCHUNK + c) * (65 * 64) + idx];
    buf[idx] = s;
  }
  __syncthreads();
  for (int idx = t; idx < 64 * 64; idx += 256)
    ctx[bh * 4096 + idx] = buf[idx] / buf[64 * 64 + (idx >> 6)];
}

// -------- MbigT[b][c][h*64+d] (bf16) = Σ_e ctx[b,h,d,e] * Wo[h*64+e][c] -----
__launch_bounds__(256)
__global__ void mbigT_kernel(const float* __restrict__ ctx, const float* __restrict__ Wo,
                             u16* __restrict__ MbigT) {
  __shared__ float Clds[64][65];
  __shared__ float Wlds2[64][64];
  const int t = threadIdx.x;
  const int tx = t & 15, ty = t >> 4;
  const int cc = blockIdx.x;  // 0..7 col chunk of 64
  const int bh = blockIdx.y;  // 0..15
  const int b = bh >> 3, h = bh & 7;
  const float* ch = ctx + bh * 4096;
  for (int i4 = t; i4 < 1024; i4 += 256) {
    const int r = i4 >> 4, c = (i4 & 15) << 2;
    const float4 v = *(const float4*)(ch + (r << 6) + c);
    Clds[r][c] = v.x; Clds[r][c + 1] = v.y; Clds[r][c + 2] = v.z; Clds[r][c + 3] = v.w;
    const float4 wv = *(const float4*)(Wo + (h * 64 + r) * D_MODEL + cc * 64 + c);
    Wlds2[r][c] = wv.x; Wlds2[r][c + 1] = wv.y; Wlds2[r][c + 2] = wv.z; Wlds2[r][c + 3] = wv.w;
  }
  __syncthreads();
  float acc[4][4] = {};
#pragma unroll 8
  for (int k = 0; k < 64; ++k) {
    float a[4], w[4];
#pragma unroll
    for (int i = 0; i < 4; ++i) a[i] = Clds[(ty << 2) + i][k];
#pragma unroll
    for (int j = 0; j < 4; ++j) w[j] = Wlds2[k][(tx << 2) + j];
#pragma unroll
    for (int i = 0; i < 4; ++i)
#pragma unroll
      for (int j = 0; j < 4; ++j) acc[i][j] = fmaf(a[i], w[j], acc[i][j]);
  }
  u16* mp = MbigT + b * D_MODEL * D_MODEL;
#pragma unroll
  for (int i = 0; i < 4; ++i)
#pragma unroll
    for (int j = 0; j < 4; ++j)
      mp[(cc * 64 + (tx << 2) + j) * D_MODEL + h * 64 + (ty << 2) + i] = f2bf(acc[i][j]);
}

__global__ void sentinel_kernel(float* out) { out[0] = 1.0e9f; }

extern "C" void kernel_launch(void* const* d_in, const int* in_sizes, int n_in,
                              void* d_out, int out_size, void* d_ws, size_t ws_size,
                              hipStream_t stream) {
  const float* query = (const float*)d_in[0];
  const float* key   = (const float*)d_in[1];
  const float* value = (const float*)d_in[2];
  const float* Wq = (const float*)d_in[3];
  const float* bq = (const float*)d_in[4];
  const float* Wk = (const float*)d_in[5];
  const float* bk = (const float*)d_in[6];
  const float* Wv = (const float*)d_in[7];
  const float* bv = (const float*)d_in[8];
  const float* Wo = (const float*)d_in[9];
  const float* bo = (const float*)d_in[10];
  float* out = (float*)d_out;
  char* ws = (char*)d_ws;

  if (ws_size < (size_t)WS_NEEDED) {
    sentinel_kernel<<<1, 1, 0, stream>>>(out);
    return;
  }

  u16* expk   = (u16*)(ws + EXPK_OFF);
  u16* vp     = (u16*)(ws + VP_OFF);
  float* part = (float*)(ws + PART_OFF);
  float* ctx  = (float*)(ws + CTX_OFF);
  u16* WTk    = (u16*)(ws + WTK_OFF);
  u16* WTv    = (u16*)(ws + WTV_OFF);
  u16* WTq    = (u16*)(ws + WTQ_OFF);    // aliases dead PART
  u16* MbigT  = (u16*)(ws + MBIGT_OFF);  // aliases dead PART
  u16* qsm    = (u16*)(ws + EXPK_OFF);   // aliases dead expk

  const dim3 blk(256), gw(8, 8), gg(1024);

  wcvt_kernel<<<gw, blk, 0, stream>>>(Wk, WTk);
  wcvt_kernel<<<gw, blk, 0, stream>>>(Wv, WTv);
  gemm_kernel<1, false><<<gg, blk, 0, stream>>>(key, WTk, bk, expk);
  gemm_kernel<2, false><<<gg, blk, 0, stream>>>(value, WTv, bv, vp);
  ctx_partial_kernel<<<dim3(NCHUNK, BATCH * NHEAD), blk, 0, stream>>>(expk, vp, part);
  ctx_reduce_kernel<<<BATCH * NHEAD, 256, 0, stream>>>(part, ctx);
  wcvt_kernel<<<gw, blk, 0, stream>>>(Wq, WTq);              // PART now dead
  mbigT_kernel<<<dim3(8, BATCH * NHEAD), blk, 0, stream>>>(ctx, Wo, MbigT);
  gemm_kernel<0, false><<<gg, blk, 0, stream>>>(query, WTq, bq, qsm);  // expk dead
  gemm_kernel<3, true><<<gg, blk, 0, stream>>>(qsm, MbigT, bo, out);
}

// Round 3
// 324.139 us; speedup vs baseline: 3.3723x; 1.2557x over previous
//
#include <hip/hip_runtime.h>

// Linear attention (Shen 2018), B=2, N=16384, D=512, H=8, DK=64.
// Round 3: full fusion.
//   phase1: per 32-row block: E=exp(K@Wk+bk), V=V@Wv+bv (B-frags from L2),
//           transposed-store E^T/V^T per head in LDS, partial E^T V -> bf16.
//   reduce: ctx = (sum partials) / (sum colsums)
//   mbigT : MbigT[b][c][h*64+d] = (ctx_h @ Wo_h)^T  (bf16)
//   phase3: per 32-row block: S^T = WqT_h @ Q^T, lane-local softmax /8,
//           P -> LDS; out^T = MbigT @ P^T; +bo -> f32 out.
// Intermediates expk/vp/qsm never touch HBM.

using u16 = unsigned short;
typedef __attribute__((ext_vector_type(8))) short bf16x8;
typedef __attribute__((ext_vector_type(4))) float f32x4;

#define D_MODEL 512
#define SEQ 16384
#define ROWS 32768
#define BLKROWS 32
#define NBLK 1024   // 32-row blocks; b = blk >> 9

// ---- ws layout (bytes); total 72,089,600 <= 76,939,264 (known-safe) ----
#define PART_OFF 0u            // bf16 [1024][8][64][64] = 67,108,864
#define SUMS_OFF 67108864u     // f32  [1024][8][64]     = 2,097,152
#define CTX_OFF  69206016u     // f32  [16][64][64]      = 262,144
#define WTK_OFF  69468160u     // bf16 512x512           = 524,288
#define WTV_OFF  69992448u
#define WTQ_OFF  70516736u
#define MBIGT_OFF 71041024u    // bf16 [2][512][512]     = 1,048,576
#define WS_NEEDED 72089600u

__device__ __forceinline__ float bf2f(u16 u) {
  union { unsigned int i; float f; } x; x.i = ((unsigned int)u) << 16; return x.f;
}
__device__ __forceinline__ u16 f2bf(float f) {
  union { float ff; unsigned int i; } x; x.ff = f;
  unsigned int r = x.i + 0x7fffu + ((x.i >> 16) & 1u);  // RNE
  return (u16)(r >> 16);
}
__device__ __forceinline__ unsigned int pk2(float lo, float hi) {
  return (unsigned int)f2bf(lo) | ((unsigned int)f2bf(hi) << 16);
}
// swizzled 16B LDS read: row-major tile, byte XOR ((row&mask)<<4)
__device__ __forceinline__ bf16x8 ldsrd(const u16* base, int row, int rowbytes,
                                        int kbyte, int mask) {
  return *(const bf16x8*)((const char*)base + row * rowbytes + (kbyte ^ ((row & mask) << 4)));
}

// ---------------- transpose+convert: out[c][r] (bf16) = in[r][c] (f32) ------
__launch_bounds__(256)
__global__ void wcvt_kernel(const float* __restrict__ in, u16* __restrict__ out) {
  __shared__ float S[64][65];
  const int t = threadIdx.x;
  const int i0 = blockIdx.y << 6, j0 = blockIdx.x << 6;
#pragma unroll
  for (int ii = 0; ii < 4; ++ii) {
    const int idx = t + ii * 256;
    const int r = idx >> 4, c4 = (idx & 15) << 2;
    const float4 v = *(const float4*)(in + (i0 + r) * D_MODEL + j0 + c4);
    S[r][c4] = v.x; S[r][c4 + 1] = v.y; S[r][c4 + 2] = v.z; S[r][c4 + 3] = v.w;
  }
  __syncthreads();
#pragma unroll
  for (int ii = 0; ii < 4; ++ii) {
    const int idx = t + ii * 256;
    const int c = idx >> 4, r4 = (idx & 15) << 2;
    ushort4 o;
    o.x = f2bf(S[r4][c]); o.y = f2bf(S[r4 + 1][c]);
    o.z = f2bf(S[r4 + 2][c]); o.w = f2bf(S[r4 + 3][c]);
    *(ushort4*)(out + (j0 + c) * D_MODEL + i0 + r4) = o;
  }
}

// ---------------- phase 1: fused K/V projection + per-head E^T V ------------
__launch_bounds__(512)
__global__ void phase1_kernel(const float* __restrict__ key, const float* __restrict__ value,
                              const u16* __restrict__ WTk, const u16* __restrict__ WTv,
                              const float* __restrict__ bkp, const float* __restrict__ bvp,
                              u16* __restrict__ part, float* __restrict__ sums) {
  __shared__ __align__(16) u16 smem[32768];  // 64KB
  u16* ET = smem;            // [wave][64 d][32 n], 2048 u16 each (rows 64B, swz mask 3)
  u16* RB = smem + 16384;    // slices: 2 x 2048 u16; later VT: [wave] x 2048 u16
  const int t = threadIdx.x;
  const int lane = t & 63, w = t >> 6;
  const int g = lane >> 4, lc = lane & 15;
  const int blk = blockIdx.x;
  const int row0 = blk * BLKROWS;
  const int c0 = w << 6;
  const int srow = t >> 4;                    // 0..31
  const int sk0 = (t & 15) << 2;              // 0..60 (f32 elems)
  const int sbyte = srow * 128 + (((t & 15) << 3) ^ ((srow & 7) << 4));

  float4 ld;
  f32x4 acc[2][4];

  auto SLOAD = [&](const float* src, int ks) {
    ld = *(const float4*)(src + (size_t)(row0 + srow) * D_MODEL + ks * 64 + sk0);
  };
  auto SWRITE = [&](int buf) {
    *(uint2*)((char*)(RB + buf * 2048) + sbyte) = make_uint2(pk2(ld.x, ld.y), pk2(ld.z, ld.w));
  };
  auto GEMM = [&](const float* src, const u16* WT) {
#pragma unroll
    for (int m = 0; m < 2; ++m)
#pragma unroll
      for (int n = 0; n < 4; ++n) acc[m][n] = (f32x4){0.f, 0.f, 0.f, 0.f};
    SLOAD(src, 0); SWRITE(0); __syncthreads();
    for (int ks = 0; ks < 8; ++ks) {
      if (ks < 7) SLOAD(src, ks + 1);
      const u16* S = RB + (ks & 1) * 2048;
#pragma unroll
      for (int kk = 0; kk < 2; ++kk) {
        bf16x8 af[2], bfr[4];
#pragma unroll
        for (int m = 0; m < 2; ++m) af[m] = ldsrd(S, m * 16 + lc, 128, kk * 64 + g * 16, 7);
#pragma unroll
        for (int n = 0; n < 4; ++n)
          bfr[n] = *(const bf16x8*)(WT + (size_t)(c0 + n * 16 + lc) * D_MODEL + ks * 64 + kk * 32 + g * 8);
#pragma unroll
        for (int m = 0; m < 2; ++m)
#pragma unroll
          for (int n = 0; n < 4; ++n)
            acc[m][n] = __builtin_amdgcn_mfma_f32_16x16x32_bf16(af[m], bfr[n], acc[m][n], 0, 0, 0);
      }
      if (ks < 7) { SWRITE((ks + 1) & 1); __syncthreads(); }
    }
  };

  // ---- E = exp(K@Wk + bk) ----
  GEMM(key, WTk);
  {
    u16* ETw = ET + w * 2048;
#pragma unroll
    for (int nf = 0; nf < 4; ++nf) {
      const float bb = bkp[c0 + nf * 16 + lc];
      float s = 0.f;
#pragma unroll
      for (int m = 0; m < 2; ++m)
#pragma unroll
        for (int r = 0; r < 4; ++r) {
          const float v = __expf(acc[m][nf][r] + bb);
          acc[m][nf][r] = v; s += v;
        }
      s += __shfl_xor(s, 16); s += __shfl_xor(s, 32);
      const int d = nf * 16 + lc;
      if (g == 0) sums[(size_t)(blk * 8 + w) * 64 + d] = s;
#pragma unroll
      for (int m = 0; m < 2; ++m) {
        const uint2 pw = make_uint2(pk2(acc[m][nf][0], acc[m][nf][1]),
                                    pk2(acc[m][nf][2], acc[m][nf][3]));
        *(uint2*)((char*)ETw + d * 64 + ((m * 32 + g * 8) ^ ((d & 3) << 4))) = pw;
      }
    }
  }
  __syncthreads();            // all E slice reads done before V staging
  // ---- V = V@Wv + bv ----
  GEMM(value, WTv);
  __syncthreads();            // all V slice reads done before VT overwrites RB
  {
    u16* VTw = RB + w * 2048;
#pragma unroll
    for (int nf = 0; nf < 4; ++nf) {
      const float bb = bvp[c0 + nf * 16 + lc];
      const int e = nf * 16 + lc;
#pragma unroll
      for (int m = 0; m < 2; ++m) {
        const uint2 pw = make_uint2(pk2(acc[m][nf][0] + bb, acc[m][nf][1] + bb),
                                    pk2(acc[m][nf][2] + bb, acc[m][nf][3] + bb));
        *(uint2*)((char*)VTw + e * 64 + ((m * 32 + g * 8) ^ ((e & 3) << 4))) = pw;
      }
    }
  }
  // ---- partial[d][e] = E^T V  (k = 32 rows) ----
  {
    const u16* ETw = ET + w * 2048;
    const u16* VTw = RB + w * 2048;
    bf16x8 paf[4], pbf[4];
#pragma unroll
    for (int dm = 0; dm < 4; ++dm) paf[dm] = ldsrd(ETw, dm * 16 + lc, 64, g * 16, 3);
#pragma unroll
    for (int em = 0; em < 4; ++em) pbf[em] = ldsrd(VTw, em * 16 + lc, 64, g * 16, 3);
    f32x4 pacc[4][4];
#pragma unroll
    for (int dm = 0; dm < 4; ++dm)
#pragma unroll
      for (int em = 0; em < 4; ++em)
        pacc[dm][em] = __builtin_amdgcn_mfma_f32_16x16x32_bf16(paf[dm], pbf[em],
                         (f32x4){0.f, 0.f, 0.f, 0.f}, 0, 0, 0);
    u16* pp = part + (size_t)(blk * 8 + w) * 4096;
#pragma unroll
    for (int dm = 0; dm < 4; ++dm)
#pragma unroll
      for (int em = 0; em < 4; ++em)
#pragma unroll
        for (int r = 0; r < 4; ++r)
          pp[(dm * 16 + g * 4 + r) * 64 + em * 16 + lc] = f2bf(pacc[dm][em][r]);
  }
}

// ---------------- phase 2: reduce partials -> ctx ---------------------------
__launch_bounds__(256)
__global__ void reduce_kernel(const u16* __restrict__ part, const float* __restrict__ sums,
                              float* __restrict__ ctx) {
  const int dg = blockIdx.x, bh = blockIdx.y;
  const int b = bh >> 3, h = bh & 7;
  const int t = threadIdx.x, dl = t >> 6, e = t & 63;
  const int d = dg * 4 + dl;
  float a = 0.f;
#pragma unroll 8
  for (int k = 0; k < 512; ++k) {
    const int gb = b * 512 + k;
    a += bf2f(part[(size_t)(gb * 8 + h) * 4096 + d * 64 + e]);
  }
  float s = 0.f;
#pragma unroll
  for (int i = 0; i < 8; ++i) {
    const int gb = b * 512 + e + i * 64;
    s += sums[(size_t)(gb * 8 + h) * 64 + d];
  }
#pragma unroll
  for (int m = 1; m < 64; m <<= 1) s += __shfl_xor(s, m);
  ctx[(size_t)bh * 4096 + d * 64 + e] = a / s;
}

// -------- MbigT[b][c][h*64+d] (bf16) = sum_e ctx[b,h,d,e] * Wo[h*64+e][c] ---
__launch_bounds__(256)
__global__ void mbigT_kernel(const float* __restrict__ ctx, const float* __restrict__ Wo,
                             u16* __restrict__ MbigT) {
  __shared__ float Clds[64][65];
  __shared__ float Wlds2[64][64];
  const int t = threadIdx.x;
  const int tx = t & 15, ty = t >> 4;
  const int cc = blockIdx.x;  // 0..7 col chunk of 64
  const int bh = blockIdx.y;  // 0..15
  const int b = bh >> 3, h = bh & 7;
  const float* ch = ctx + bh * 4096;
  for (int i4 = t; i4 < 1024; i4 += 256) {
    const int r = i4 >> 4, c = (i4 & 15) << 2;
    const float4 v = *(const float4*)(ch + (r << 6) + c);
    Clds[r][c] = v.x; Clds[r][c + 1] = v.y; Clds[r][c + 2] = v.z; Clds[r][c + 3] = v.w;
    const float4 wv = *(const float4*)(Wo + (h * 64 + r) * D_MODEL + cc * 64 + c);
    Wlds2[r][c] = wv.x; Wlds2[r][c + 1] = wv.y; Wlds2[r][c + 2] = wv.z; Wlds2[r][c + 3] = wv.w;
  }
  __syncthreads();
  float acc[4][4] = {};
#pragma unroll 8
  for (int k = 0; k < 64; ++k) {
    float a[4], wv[4];
#pragma unroll
    for (int i = 0; i < 4; ++i) a[i] = Clds[(ty << 2) + i][k];
#pragma unroll
    for (int j = 0; j < 4; ++j) wv[j] = Wlds2[k][(tx << 2) + j];
#pragma unroll
    for (int i = 0; i < 4; ++i)
#pragma unroll
      for (int j = 0; j < 4; ++j) acc[i][j] = fmaf(a[i], wv[j], acc[i][j]);
  }
  u16* mp = MbigT + b * D_MODEL * D_MODEL;
#pragma unroll
  for (int i = 0; i < 4; ++i)
#pragma unroll
    for (int j = 0; j < 4; ++j)
      mp[(cc * 64 + (tx << 2) + j) * D_MODEL + h * 64 + (ty << 2) + i] = f2bf(acc[i][j]);
}

// ---------------- phase 3: fused Q projection/softmax + output GEMM ---------
__launch_bounds__(512)
__global__ void phase3_kernel(const float* __restrict__ query, const u16* __restrict__ WTq,
                              const float* __restrict__ bqp, const u16* __restrict__ MbigT,
                              const float* __restrict__ bop, float* __restrict__ out) {
  __shared__ __align__(16) u16 smem[20480];  // 40KB
  u16* SL = smem;          // slices: 2 x 2048 u16
  u16* P  = smem + 4096;   // [32 n][512 k], rows 1024B, swz mask 7
  const int t = threadIdx.x;
  const int lane = t & 63, w = t >> 6;
  const int g = lane >> 4, lc = lane & 15;
  const int blk = blockIdx.x;
  const int n0 = blk * BLKROWS;
  const int b = blk >> 9;
  const int c0 = w << 6;
  const int srow = t >> 4;
  const int sk0 = (t & 15) << 2;
  const int sbyte = srow * 128 + (((t & 15) << 3) ^ ((srow & 7) << 4));

  float4 ld;
  auto SLOAD = [&](int ks) {
    ld = *(const float4*)(query + (size_t)(n0 + srow) * D_MODEL + ks * 64 + sk0);
  };
  auto SWRITE = [&](int buf) {
    *(uint2*)((char*)(SL + buf * 2048) + sbyte) = make_uint2(pk2(ld.x, ld.y), pk2(ld.z, ld.w));
  };

  // ---- S^T = WqT_h @ Q^T : acc[mf][nf], d = mf*16+g*4+r (head col), n = nf*16+lc
  f32x4 acc[4][2];
#pragma unroll
  for (int m = 0; m < 4; ++m)
#pragma unroll
    for (int n = 0; n < 2; ++n) acc[m][n] = (f32x4){0.f, 0.f, 0.f, 0.f};
  SLOAD(0); SWRITE(0); __syncthreads();
  for (int ks = 0; ks < 8; ++ks) {
    if (ks < 7) SLOAD(ks + 1);
    const u16* S = SL + (ks & 1) * 2048;
#pragma unroll
    for (int kk = 0; kk < 2; ++kk) {
      bf16x8 af[4], bfr[2];
#pragma unroll
      for (int m = 0; m < 4; ++m)
        af[m] = *(const bf16x8*)(WTq + (size_t)(c0 + m * 16 + lc) * D_MODEL + ks * 64 + kk * 32 + g * 8);
#pragma unroll
      for (int n = 0; n < 2; ++n) bfr[n] = ldsrd(S, n * 16 + lc, 128, kk * 64 + g * 16, 7);
#pragma unroll
      for (int m = 0; m < 4; ++m)
#pragma unroll
        for (int n = 0; n < 2; ++n)
          acc[m][n] = __builtin_amdgcn_mfma_f32_16x16x32_bf16(af[m], bfr[n], acc[m][n], 0, 0, 0);
    }
    if (ks < 7) { SWRITE((ks + 1) & 1); __syncthreads(); }
  }
  // ---- softmax over d (per n), * 1/8, bf16 -> P_lds ----
  {
    float bqv[4][4];
#pragma unroll
    for (int m = 0; m < 4; ++m)
#pragma unroll
      for (int r = 0; r < 4; ++r) bqv[m][r] = bqp[c0 + m * 16 + g * 4 + r];
#pragma unroll
    for (int nf = 0; nf < 2; ++nf) {
      float mx = -3.0e38f;
#pragma unroll
      for (int m = 0; m < 4; ++m)
#pragma unroll
        for (int r = 0; r < 4; ++r) {
          const float v = acc[m][nf][r] + bqv[m][r];
          acc[m][nf][r] = v; mx = fmaxf(mx, v);
        }
      mx = fmaxf(mx, __shfl_xor(mx, 16)); mx = fmaxf(mx, __shfl_xor(mx, 32));
      float s = 0.f;
#pragma unroll
      for (int m = 0; m < 4; ++m)
#pragma unroll
        for (int r = 0; r < 4; ++r) {
          const float e = __expf(acc[m][nf][r] - mx);
          acc[m][nf][r] = e; s += e;
        }
      s += __shfl_xor(s, 16); s += __shfl_xor(s, 32);
      const float f = 0.125f / s;
      const int n = nf * 16 + lc;
#pragma unroll
      for (int m = 0; m < 4; ++m) {
        const uint2 pw = make_uint2(pk2(acc[m][nf][0] * f, acc[m][nf][1] * f),
                                    pk2(acc[m][nf][2] * f, acc[m][nf][3] * f));
        *(uint2*)((char*)P + n * 1024 + ((w * 128 + m * 32 + g * 8) ^ ((n & 7) << 4))) = pw;
      }
    }
  }
  __syncthreads();
  // ---- out^T = MbigT[b] @ P^T : oc[mf][nf], c = c0+mf*16+g*4+r, n = nf*16+lc
  f32x4 oc[4][2];
#pragma unroll
  for (int m = 0; m < 4; ++m)
#pragma unroll
    for (int n = 0; n < 2; ++n) oc[m][n] = (f32x4){0.f, 0.f, 0.f, 0.f};
  const u16* MT = MbigT + (size_t)b * D_MODEL * D_MODEL;
  for (int ks = 0; ks < 16; ++ks) {
    bf16x8 af[4], bfr[2];
#pragma unroll
    for (int m = 0; m < 4; ++m)
      af[m] = *(const bf16x8*)(MT + (size_t)(c0 + m * 16 + lc) * D_MODEL + ks * 32 + g * 8);
#pragma unroll
    for (int n = 0; n < 2; ++n) bfr[n] = ldsrd(P, n * 16 + lc, 1024, ks * 64 + g * 16, 7);
#pragma unroll
    for (int m = 0; m < 4; ++m)
#pragma unroll
      for (int n = 0; n < 2; ++n)
        oc[m][n] = __builtin_amdgcn_mfma_f32_16x16x32_bf16(af[m], bfr[n], oc[m][n], 0, 0, 0);
  }
  {
    float bov[4][4];
#pragma unroll
    for (int m = 0; m < 4; ++m)
#pragma unroll
      for (int r = 0; r < 4; ++r) bov[m][r] = bop[c0 + m * 16 + g * 4 + r];
#pragma unroll
    for (int m = 0; m < 4; ++m)
#pragma unroll
      for (int nf = 0; nf < 2; ++nf) {
        float4 o;
        o.x = oc[m][nf][0] + bov[m][0]; o.y = oc[m][nf][1] + bov[m][1];
        o.z = oc[m][nf][2] + bov[m][2]; o.w = oc[m][nf][3] + bov[m][3];
        *(float4*)(out + (size_t)(n0 + nf * 16 + lc) * D_MODEL + c0 + m * 16 + g * 4) = o;
      }
  }
}

__global__ void sentinel_kernel(float* out) { out[0] = 1.0e9f; }

extern "C" void kernel_launch(void* const* d_in, const int* in_sizes, int n_in,
                              void* d_out, int out_size, void* d_ws, size_t ws_size,
                              hipStream_t stream) {
  const float* query = (const float*)d_in[0];
  const float* key   = (const float*)d_in[1];
  const float* value = (const float*)d_in[2];
  const float* Wq = (const float*)d_in[3];
  const float* bq = (const float*)d_in[4];
  const float* Wk = (const float*)d_in[5];
  const float* bk = (const float*)d_in[6];
  const float* Wv = (const float*)d_in[7];
  const float* bv = (const float*)d_in[8];
  const float* Wo = (const float*)d_in[9];
  const float* bo = (const float*)d_in[10];
  float* out = (float*)d_out;
  char* ws = (char*)d_ws;

  if (ws_size < (size_t)WS_NEEDED) {
    sentinel_kernel<<<1, 1, 0, stream>>>(out);
    return;
  }

  u16* part   = (u16*)(ws + PART_OFF);
  float* sums = (float*)(ws + SUMS_OFF);
  float* ctx  = (float*)(ws + CTX_OFF);
  u16* WTk    = (u16*)(ws + WTK_OFF);
  u16* WTv    = (u16*)(ws + WTV_OFF);
  u16* WTq    = (u16*)(ws + WTQ_OFF);
  u16* MbigT  = (u16*)(ws + MBIGT_OFF);

  const dim3 blk256(256), gw(8, 8);
  wcvt_kernel<<<gw, blk256, 0, stream>>>(Wk, WTk);
  wcvt_kernel<<<gw, blk256, 0, stream>>>(Wv, WTv);
  wcvt_kernel<<<gw, blk256, 0, stream>>>(Wq, WTq);
  phase1_kernel<<<NBLK, 512, 0, stream>>>(key, value, WTk, WTv, bk, bv, part, sums);
  reduce_kernel<<<dim3(16, 16), blk256, 0, stream>>>(part, sums, ctx);
  mbigT_kernel<<<dim3(8, 16), blk256, 0, stream>>>(ctx, Wo, MbigT);
  phase3_kernel<<<NBLK, 512, 0, stream>>>(query, WTq, bq, MbigT, bo, out);
}